// Round 1
// baseline (355.695 us; speedup 1.0000x reference)
//
#include <hip/hip_runtime.h>

typedef short short8 __attribute__((ext_vector_type(8)));
typedef __bf16 bf16x8 __attribute__((ext_vector_type(8)));
typedef float floatx4 __attribute__((ext_vector_type(4)));

__device__ __forceinline__ float make_pow2(int e) {
  return __builtin_bit_cast(float, (unsigned)((e + 127) << 23));
}

// ---------------- Phase 1: quantize weights -> bf16 in workspace ----------------
// w: [256,1152] fp32 (row = C_out, col = c*9+i*3+j). 4608 waves: one per (row, kblock).
__global__ void quant_w_kernel(const float* __restrict__ w, unsigned short* __restrict__ qw) {
  int b = blockIdx.x;                 // 0..4607
  int row = b / 18, kb = b - row * 18;
  int t = threadIdx.x;                // 0..63
  int idx = row * 1152 + kb * 64 + t;
  float v = w[idx];
  float a = fabsf(v);
  #pragma unroll
  for (int off = 32; off; off >>= 1) a = fmaxf(a, __shfl_xor(a, off));
  float q = 0.f;
  if (a > 0.f) {
    int e = (int)((__builtin_bit_cast(unsigned, a) >> 23) & 0xffu) - 127;
    if (e < -126) e = -126;
    float inv = make_pow2(6 - e);   // 2^(6-e)
    float s   = make_pow2(e - 6);   // 2^(e-6)
    float r = rintf(v * inv);       // round-half-even == jnp.round
    r = fminf(fmaxf(r, -128.f), 127.f);
    q = r * s;                      // exactly representable in bf16
  }
  qw[idx] = (unsigned short)(__builtin_bit_cast(unsigned, q) >> 16);
}

// ---------------- Phase 2: fused im2col + BFP-quantize + GEMM ----------------
// M=100352 pixels, N=256 Cout, K=1152. Tiles: BM=64, BN=64, BK=64 (== BFP block).
// 256 threads = 4 waves (2x2 of 32x32). Grid: 1568 * 4.
__global__ __launch_bounds__(256) void conv_bfp_kernel(
    const float* __restrict__ in, const unsigned short* __restrict__ qw,
    const float* __restrict__ bias, float* __restrict__ out) {
  __shared__ unsigned short As[64 * 64];   // [m][k] bf16, XOR-swizzled 16B chunks
  __shared__ unsigned short Bs[64 * 64];   // [n][k] bf16, XOR-swizzled
  __shared__ float pmax[4][64];

  const int bid = blockIdx.x;
  const int nt = bid & 3;       // N tile (consecutive blocks share mt -> L2 reuse of input)
  const int mt = bid >> 2;      // M tile 0..1567
  const int t = threadIdx.x;
  const int lane = t & 63;
  const int wave = t >> 6;

  // A-load geometry: row m = lane (coalesced along x), k-range = wave*16..+15
  const unsigned m = mt * 64 + lane;
  const unsigned nimg = m / 3136u;
  const unsigned py = m - nimg * 3136u;
  const int y = (int)(py / 56u);
  const int x = (int)(py - (unsigned)y * 56u);
  const float* inp = in + (size_t)nimg * 401408u;   // 128*3136

  // B-load geometry: 16 bf16 per thread
  const int bn_row = t >> 2;           // 0..63
  const int bn_k = (t & 3) * 16;       // element offset in K

  const int wm = wave >> 1, wn = wave & 1;
  const int lr = lane & 15;
  const int lk = (lane >> 4) << 4;     // byte offset of this lane's 8-bf16 K-chunk

  floatx4 acc[2][2] = {};

  for (int kb = 0; kb < 18; ++kb) {
    // ---- global loads: A raw fp32 gather (+ local max), B pre-quantized bf16 ----
    float av[16];
    float lmax = 0.f;
    const int k0 = kb * 64 + wave * 16;
    #pragma unroll
    for (int u = 0; u < 16; ++u) {
      int k = k0 + u;
      int c = (int)((unsigned)k / 9u);
      int ij = k - c * 9;
      int i = (int)((unsigned)ij / 3u);
      int j = ij - i * 3;
      int yy = y + i - 1, xx = x + j - 1;
      float v = 0.f;
      if ((unsigned)yy < 56u && (unsigned)xx < 56u)
        v = inp[c * 3136 + yy * 56 + xx];
      av[u] = v;
      lmax = fmaxf(lmax, fabsf(v));
    }
    const unsigned short* qwp = qw + (size_t)(nt * 64 + bn_row) * 1152 + kb * 64 + bn_k;
    short8 bv0 = *(const short8*)(qwp);
    short8 bv1 = *(const short8*)(qwp + 8);

    pmax[wave][lane] = lmax;
    __syncthreads();   // B1: pmax ready; prev-iter MFMA reads done before LDS overwrite

    // ---- quantize A row-block (row = lane, 16 k-values) ----
    float ma = fmaxf(fmaxf(pmax[0][lane], pmax[1][lane]),
                     fmaxf(pmax[2][lane], pmax[3][lane]));
    short8 aq0, aq1;
    if (ma > 0.f) {
      int e = (int)((__builtin_bit_cast(unsigned, ma) >> 23) & 0xffu) - 127;
      if (e < -126) e = -126;
      float inv = make_pow2(6 - e);
      float s   = make_pow2(e - 6);
      #pragma unroll
      for (int u = 0; u < 16; ++u) {
        float r = rintf(av[u] * inv);
        r = fminf(fmaxf(r, -128.f), 127.f);
        float q = r * s;
        unsigned short hb = (unsigned short)(__builtin_bit_cast(unsigned, q) >> 16);
        if (u < 8) aq0[u] = (short)hb; else aq1[u - 8] = (short)hb;
      }
    } else {
      aq0 = (short8)0; aq1 = (short8)0;
    }
    {
      char* arow = (char*)As + lane * 128;
      int kx = wave * 32;                       // byte offset of this thread's 16 k's
      *(short8*)(arow + ((kx)      ^ ((lane & 7) << 4))) = aq0;
      *(short8*)(arow + ((kx + 16) ^ ((lane & 7) << 4))) = aq1;
      char* brow = (char*)Bs + bn_row * 128;
      int kxb = bn_k * 2;
      *(short8*)(brow + ((kxb)      ^ ((bn_row & 7) << 4))) = bv0;
      *(short8*)(brow + ((kxb + 16) ^ ((bn_row & 7) << 4))) = bv1;
    }
    __syncthreads();   // B2: tiles ready

    // ---- MFMA: 2x2 frags x 2 k-subs ----
    #pragma unroll
    for (int ks = 0; ks < 2; ++ks) {
      bf16x8 af[2], bfr[2];
      #pragma unroll
      for (int f = 0; f < 2; ++f) {
        int ar = wm * 32 + f * 16 + lr;
        af[f] = __builtin_bit_cast(bf16x8,
            *(const short8*)((const char*)As + ar * 128 + ((ks * 64 + lk) ^ ((ar & 7) << 4))));
        int br = wn * 32 + f * 16 + lr;
        bfr[f] = __builtin_bit_cast(bf16x8,
            *(const short8*)((const char*)Bs + br * 128 + ((ks * 64 + lk) ^ ((br & 7) << 4))));
      }
      #pragma unroll
      for (int fm = 0; fm < 2; ++fm)
        #pragma unroll
        for (int fn = 0; fn < 2; ++fn)
          acc[fm][fn] = __builtin_amdgcn_mfma_f32_16x16x32_bf16(af[fm], bfr[fn], acc[fm][fn], 0, 0, 0);
    }
  }

  // ---- epilogue: bias + scatter store (out[n][co][y][x]) ----
  #pragma unroll
  for (int fn = 0; fn < 2; ++fn) {
    int co = nt * 64 + wn * 32 + fn * 16 + lr;
    float bco = bias[co];
    #pragma unroll
    for (int fm = 0; fm < 2; ++fm) {
      #pragma unroll
      for (int r = 0; r < 4; ++r) {
        unsigned mm = mt * 64 + wm * 32 + fm * 16 + ((lane >> 4) << 2) + r;
        unsigned ni = mm / 3136u;
        unsigned pp = mm - ni * 3136u;
        out[(size_t)ni * 802816u + (size_t)co * 3136u + pp] = acc[fm][fn][r] + bco;
      }
    }
  }
}

extern "C" void kernel_launch(void* const* d_in, const int* in_sizes, int n_in,
                              void* d_out, int out_size, void* d_ws, size_t ws_size,
                              hipStream_t stream) {
  const float* in   = (const float*)d_in[0];
  const float* w    = (const float*)d_in[1];
  const float* bias = (const float*)d_in[2];
  float* out = (float*)d_out;
  unsigned short* qw = (unsigned short*)d_ws;   // 256*1152*2 = 589824 B

  quant_w_kernel<<<4608, 64, 0, stream>>>(w, qw);
  conv_bfp_kernel<<<1568 * 4, 256, 0, stream>>>(in, qw, bias, out);
}

// Round 2
// 151.696 us; speedup vs baseline: 2.3448x; 2.3448x over previous
//
#include <hip/hip_runtime.h>

typedef short short8 __attribute__((ext_vector_type(8)));
typedef __bf16 bf16x8 __attribute__((ext_vector_type(8)));
typedef float floatx4 __attribute__((ext_vector_type(4)));

__device__ __forceinline__ float make_pow2(int e) {
  return __builtin_bit_cast(float, (unsigned)((e + 127) << 23));
}

typedef __attribute__((address_space(3))) void lds_void;
typedef const __attribute__((address_space(1))) void glob_void;
__device__ __forceinline__ void gload_lds16(const void* g, void* l) {
  __builtin_amdgcn_global_load_lds((glob_void*)g, (lds_void*)l, 16, 0, 0);
}

// ---------------- Phase 1: quantize weights -> bf16 in workspace ----------------
__global__ void quant_w_kernel(const float* __restrict__ w, unsigned short* __restrict__ qw) {
  int b = blockIdx.x;                 // 0..4607
  int row = b / 18, kb = b - row * 18;
  int t = threadIdx.x;                // 0..63
  int idx = row * 1152 + kb * 64 + t;
  float v = w[idx];
  float a = fabsf(v);
  #pragma unroll
  for (int off = 32; off; off >>= 1) a = fmaxf(a, __shfl_xor(a, off));
  float q = 0.f;
  if (a > 0.f) {
    int e = (int)((__builtin_bit_cast(unsigned, a) >> 23) & 0xffu) - 127;
    if (e < -126) e = -126;
    float inv = make_pow2(6 - e);
    float s   = make_pow2(e - 6);
    float r = rintf(v * inv);
    r = fminf(fmaxf(r, -128.f), 127.f);
    q = r * s;
  }
  qw[idx] = (unsigned short)(__builtin_bit_cast(unsigned, q) >> 16);
}

// ---------------- Phase 2: fused im2col + BFP-quantize + GEMM ----------------
// M=100352, N=256, K=1152. BM=64, BN=256, BK=64 (== BFP block). 256 thr = 4 waves,
// each wave owns a 64-col slab (N = wave*64..+63), all 64 M rows: acc[4][4].
__global__ __launch_bounds__(256) void conv_bfp_kernel(
    const float* __restrict__ in, const unsigned short* __restrict__ qw,
    const float* __restrict__ bias, float* __restrict__ out) {
  __shared__ unsigned short As[64 * 64];    // 8 KB  [m][k] bf16, XOR-swizzled 16B chunks
  __shared__ unsigned short Bs[256 * 64];   // 32 KB [n][k] bf16, XOR-swizzled
  __shared__ float pmax[64][4];

  const int mt = blockIdx.x;
  const int t = threadIdx.x;
  const int lane = t & 63;
  const int wave = __builtin_amdgcn_readfirstlane(t >> 6);

  // ---- pixel geometry (row m = lane; coalesced along x) ----
  const unsigned m = mt * 64u + lane;
  const unsigned nimg = m / 3136u;
  const unsigned py = m - nimg * 3136u;
  const int y = (int)(py / 56u);
  const int x = (int)(py - (unsigned)y * 56u);
  // byte offset of center pixel within the image tensor
  const int vbase = (int)((nimg * 401408u + (unsigned)y * 56u + (unsigned)x) * 4u);
  // 9-bit tap validity mask (bit ij = i*3+j)
  int vm = 0;
  #pragma unroll
  for (int i = 0; i < 3; ++i)
    #pragma unroll
    for (int j = 0; j < 3; ++j)
      if ((unsigned)(y + i - 1) < 56u && (unsigned)(x + j - 1) < 56u)
        vm |= 1 << (i * 3 + j);

  // ---- B staging geometry: wave w stages rows w*64..w*64+63 via global_load_lds ----
  // physical LDS chunk (l&7) of row (c8*8 + l>>3) must hold source chunk ((l&7)^(row&7));
  // row&7 == (l>>3) independent of c8, so per-lane source chunk is fixed.
  const int l3 = lane >> 3, l7 = lane & 7;
  const char* bsrc = (const char*)qw + (size_t)((wave * 64 + l3) * 2304) + ((l7 ^ l3) * 16);
  char* bdst = (char*)Bs + wave * 8192;

  const int lr = lane & 15;
  const int lk = (lane >> 4) << 4;            // byte offset of this lane's 8-bf16 K-chunk
  const int swz = (lr & 7) << 4;              // row-XOR swizzle (f*16 keeps row&7 == lr&7)

  floatx4 acc[4][4] = {};

  for (int kb = 0; kb < 18; ++kb) {
    // ---- A gather: 16 k-values, k wave-uniform -> all decode/addressing in SALU ----
    float av[16];
    float lmax = 0.f;
    const int k0 = __builtin_amdgcn_readfirstlane(kb * 64 + wave * 16);
    #pragma unroll
    for (int u = 0; u < 16; ++u) {
      int k = k0 + u;                          // scalar
      int c = (int)((unsigned)k / 9u);         // scalar magic-mul
      int ij = k - c * 9;                      // scalar
      int soff = c * 3136 + (ij / 3) * 56 + (ij % 3) - 57;   // scalar tap offset (elems)
      const char* pk = (const char*)in + (ptrdiff_t)soff * 4; // scalar base pointer
      float v = 0.f;
      if ((vm >> ij) & 1)                      // 1 v_lshrrev(sgpr shamt) + and + cmp
        v = *(const float*)(pk + vbase);       // global_load_dword v, vbase, s[pk]
      av[u] = v;
      lmax = fmaxf(lmax, fabsf(v));            // v_max with abs modifier
    }
    pmax[lane][wave] = lmax;
    __syncthreads();   // B1: prev MFMA reads done; pmax ready

    // ---- issue B tile loads (async -> LDS), latency hidden under quantize ----
    #pragma unroll
    for (int c8 = 0; c8 < 8; ++c8)
      gload_lds16(bsrc + (size_t)c8 * 18432 + kb * 128, bdst + c8 * 1024);

    // ---- quantize A row (row = lane, 16 k's) ----
    floatx4 pm = *(floatx4*)&pmax[lane][0];
    float ma = fmaxf(fmaxf(pm[0], pm[1]), fmaxf(pm[2], pm[3]));
    short8 aq0, aq1;
    if (ma > 0.f) {
      int e = (int)((__builtin_bit_cast(unsigned, ma) >> 23) & 0xffu) - 127;
      if (e < -126) e = -126;
      float inv = make_pow2(6 - e);
      float s   = make_pow2(e - 6);
      #pragma unroll
      for (int u = 0; u < 16; ++u) {
        float r = rintf(av[u] * inv);
        r = fminf(fmaxf(r, -128.f), 127.f);
        float q = r * s;
        unsigned short hb = (unsigned short)(__builtin_bit_cast(unsigned, q) >> 16);
        if (u < 8) aq0[u] = (short)hb; else aq1[u - 8] = (short)hb;
      }
    } else {
      aq0 = (short8)0; aq1 = (short8)0;
    }
    {
      char* arow = (char*)As + lane * 128;
      int kx = wave * 32;
      *(short8*)(arow + ((kx)      ^ ((lane & 7) << 4))) = aq0;
      *(short8*)(arow + ((kx + 16) ^ ((lane & 7) << 4))) = aq1;
    }
    __syncthreads();   // B2: As written, Bs landed (vmcnt drained by syncthreads)

    // ---- MFMA: 4x4 frags x 2 k-subs ----
    #pragma unroll
    for (int ks = 0; ks < 2; ++ks) {
      const int kbyte = (ks * 64 + lk) ^ swz;
      bf16x8 afr[4], bfr[4];
      #pragma unroll
      for (int f = 0; f < 4; ++f) {
        afr[f] = __builtin_bit_cast(bf16x8,
            *(const short8*)((const char*)As + (f * 16 + lr) * 128 + kbyte));
        bfr[f] = __builtin_bit_cast(bf16x8,
            *(const short8*)((const char*)Bs + (wave * 64 + f * 16 + lr) * 128 + kbyte));
      }
      #pragma unroll
      for (int fm = 0; fm < 4; ++fm)
        #pragma unroll
        for (int fn = 0; fn < 4; ++fn)
          acc[fm][fn] = __builtin_amdgcn_mfma_f32_16x16x32_bf16(afr[fm], bfr[fn], acc[fm][fn], 0, 0, 0);
    }
    if (kb < 17) __syncthreads();  // protect As/Bs from next iteration's writes
  }

  // ---- epilogue: bias + scatter store out[n][co][y][x] ----
  const int rg = (lane >> 4) << 2;
  #pragma unroll
  for (int fm = 0; fm < 4; ++fm) {
    unsigned ni4[4], pp4[4];
    #pragma unroll
    for (int r = 0; r < 4; ++r) {
      unsigned mm = mt * 64u + fm * 16 + rg + r;
      ni4[r] = mm / 3136u;
      pp4[r] = mm - ni4[r] * 3136u;
    }
    #pragma unroll
    for (int fn = 0; fn < 4; ++fn) {
      int co = wave * 64 + fn * 16 + lr;
      float bco = bias[co];
      #pragma unroll
      for (int r = 0; r < 4; ++r)
        out[(size_t)ni4[r] * 802816u + (size_t)co * 3136u + pp4[r]] = acc[fm][fn][r] + bco;
    }
  }
}

extern "C" void kernel_launch(void* const* d_in, const int* in_sizes, int n_in,
                              void* d_out, int out_size, void* d_ws, size_t ws_size,
                              hipStream_t stream) {
  const float* in   = (const float*)d_in[0];
  const float* w    = (const float*)d_in[1];
  const float* bias = (const float*)d_in[2];
  float* out = (float*)d_out;
  unsigned short* qw = (unsigned short*)d_ws;   // 256*1152*2 = 589824 B

  quant_w_kernel<<<4608, 64, 0, stream>>>(w, qw);
  conv_bfp_kernel<<<1568, 256, 0, stream>>>(in, qw, bias, out);
}